// Round 12
// baseline (65.347 us; speedup 1.0000x reference)
//
#include <hip/hip_runtime.h>
#include <math.h>

#define NCLS 80
#define BINS 17
#define REGMAX 16
#define NG 32
#define NB 16
#define KTOP 10
#define RAD 2.5f

// ---------- workspace layout (bytes) ----------
#define WS_ACC   0
#define WS_NPOS  32
#define WS_DFLN  224
#define WS_CNT   608
#define NBLOCKS  (67 * 16)

// focal_bce with t=0: ce*0.75*p^2   (single exp + single log)
__device__ __forceinline__ float focal0(float x) {
    float e   = __expf(-fabsf(x));
    float inv = 1.0f / (1.0f + e);
    float p   = (x >= 0.0f) ? inv : e * inv;          // sigmoid(x)
    float ce  = fmaxf(x, 0.0f) + __logf(1.0f + e);
    return ce * 0.75f * p * p;
}

__device__ __forceinline__ float focal_t(float x, float t) {
    float e   = __expf(-fabsf(x));
    float inv = 1.0f / (1.0f + e);
    float p   = (x >= 0.0f) ? inv : e * inv;
    float ce  = fmaxf(x, 0.0f) - x * t + __logf(1.0f + e);
    float pt  = p * t + (1.0f - p) * (1.0f - t);
    float at  = 0.25f * t + 0.75f * (1.0f - t);
    float om  = 1.0f - pt;
    return ce * at * om * om;
}

// ---- single fused kernel: 128-pt tiles, 8 waves, 512 thr, full occupancy ----
__global__ __launch_bounds__(512, 4) void k_main_f(
    const float* __restrict__ reg0, const float* __restrict__ cls0,
    const float* __restrict__ reg1, const float* __restrict__ cls1,
    const float* __restrict__ reg2, const float* __restrict__ cls2,
    const float* __restrict__ gtb,  const int* __restrict__ lab,
    float* __restrict__ acc, float* __restrict__ npos, float* __restrict__ dfln,
    int* __restrict__ cnt, float* __restrict__ out)
{
    int bx = blockIdx.x;
    int b  = blockIdx.y;
    int lvl, tix, W; const float *regp, *clsp; float inv_s;
    if (bx < 50)      { lvl = 0; tix = bx;      W = 80; regp = reg0; clsp = cls0; inv_s = 0.125f;   }
    else if (bx < 63) { lvl = 1; tix = bx - 50; W = 40; regp = reg1; clsp = cls1; inv_s = 0.0625f;  }
    else              { lvl = 2; tix = bx - 63; W = 20; regp = reg2; clsp = cls2; inv_s = 0.03125f; }
    int HW = W * W;
    int tile = tix * 128;

    int tid  = threadIdx.x;
    int lane = tid & 63;
    int w    = tid >> 6;                 // wave 0..7
    int p0   = tile + 2 * lane;          // this thread's 2 consecutive points
    bool v   = p0 < HW;                  // 2 | HW -> all-or-none per thread
    int pb   = v ? p0 : HW - 2;          // clamped load base

    __shared__ float s_bx[NG][6];        // x1,y1,x2,y2,gcx,gcy (scaled)
    __shared__ int   s_lab[NG];
    __shared__ float s_dv[4][128], s_lz[4][128], s_fzp[4][128], s_fzs[128];
    __shared__ unsigned char s_ps[8][64];
    __shared__ float red[8][4];
    __shared__ int   s_any, s_tick, s_fb[NG][KTOP];

    // --- stage boxes + labels ---
    if (tid == 0) s_any = 0;
    if (tid < NG) {
        int g = tid;
        float4 bb4 = *(const float4*)(gtb + (b * NG + g) * 4);
        float x1 = bb4.x * inv_s, y1 = bb4.y * inv_s;
        float x2 = bb4.z * inv_s, y2 = bb4.w * inv_s;
        s_bx[g][0] = x1; s_bx[g][1] = y1; s_bx[g][2] = x2; s_bx[g][3] = y2;
        s_bx[g][4] = (x1 + x2) * 0.5f; s_bx[g][5] = (y1 + y2) * 0.5f;
        s_lab[g] = lab[b * NG + g];
    }
    __syncthreads();

    // --- any_pos via exact windowed scan (window provably holds all positives) ---
    {
        int g = tid >> 4, wi = tid & 15;         // 16 threads per g
        float x1 = s_bx[g][0], y1 = s_bx[g][1];
        float x2 = s_bx[g][2], y2 = s_bx[g][3];
        float gcx = s_bx[g][4], gcy = s_bx[g][5];
        int jc = (int)floorf(gcx), ic = (int)floorf(gcy);
        bool any = false;
#pragma unroll
        for (int r = 0; r < 6; ++r) {
            int ci = wi + 16 * r;
            if (ci < 81) {
                int j = jc + (ci % 9) - 4, i = ic + (ci / 9) - 4;
                if (j >= 0 && j < W && i >= 0 && i < W) {
                    float cx = (float)j + 0.5f, cy = (float)i + 0.5f;
                    bool m = (cx - x1 > 0.0f) && (cy - y1 > 0.0f) &&
                             (x2 - cx > 0.0f) && (y2 - cy > 0.0f) &&
                             (cx >= gcx - RAD) && (cx <= gcx + RAD) &&
                             (cy >= gcy - RAD) && (cy <= gcy + RAD);
                    any = any || m;
                }
            }
        }
        if (__any(any) && lane == 0) atomicOr(&s_any, 1);
    }
    __syncthreads();
    bool anyb = s_any != 0;

    // --- rare fallback: exact top-10 closest cells per g (block-uniform) ---
    if (!anyb) {
        if (tid < NG) {
            int g = tid;
            float gcx = s_bx[g][4], gcy = s_bx[g][5];
            float bd[KTOP]; int bi[KTOP];
            for (int t = 0; t < KTOP; ++t) { bd[t] = 3.0e38f; bi[t] = 0; }
            for (int p = 0; p < HW; ++p) {
                float cx = (float)(p % W) + 0.5f;
                float cy = (float)(p / W) + 0.5f;
                float dx = cx - gcx, dy = cy - gcy;
                float d = dx * dx + dy * dy;
                if (d < bd[KTOP - 1]) {
                    int t = KTOP - 1;
                    while (t > 0 && d < bd[t - 1]) { bd[t] = bd[t-1]; bi[t] = bi[t-1]; --t; }
                    bd[t] = d; bi[t] = p;
                }
            }
            for (int t = 0; t < KTOP; ++t) s_fb[g][t] = bi[t];
        }
        __syncthreads();
    }

    // --- streaming: waves 0-3 = one DFL dist each (online LSE, 2-deep prefetch);
    //     waves 4-7 = 20 focal classes each (4-wide load groups) ---
    if (w < 4) {
        const float* bp = regp + (size_t)(b * 68 + w * BINS) * HW + pb;
        float m0 = -3.0e38f, m1 = -3.0e38f, s0 = 0.f, s1 = 0.f, e0 = 0.f, e1 = 0.f;
        float2 cur = *(const float2*)bp;
#pragma unroll
        for (int t = 0; t < BINS; ++t) {
            float2 nxt = (t < BINS - 1) ? *(const float2*)(bp + (size_t)(t + 1) * HW)
                                        : make_float2(0.f, 0.f);
            float nm0 = fmaxf(m0, cur.x);
            float a0  = __expf(m0 - nm0), b0 = __expf(cur.x - nm0);
            s0 = s0 * a0 + b0; e0 = e0 * a0 + b0 * (float)t; m0 = nm0;
            float nm1 = fmaxf(m1, cur.y);
            float a1  = __expf(m1 - nm1), b1 = __expf(cur.y - nm1);
            s1 = s1 * a1 + b1; e1 = e1 * a1 + b1 * (float)t; m1 = nm1;
            cur = nxt;
        }
        s_dv[w][2*lane]   = e0 / s0;  s_lz[w][2*lane]   = __logf(s0) + m0;
        s_dv[w][2*lane+1] = e1 / s1;  s_lz[w][2*lane+1] = __logf(s1) + m1;
    } else {
        int q = w - 4;
        const float* bp = clsp + (size_t)(b * 80 + q * 20) * HW + pb;
        float fz0 = 0.f, fz1 = 0.f;
#pragma unroll
        for (int t = 0; t < 20; t += 4) {
            float2 c0 = *(const float2*)(bp + (size_t)(t    ) * HW);
            float2 c1 = *(const float2*)(bp + (size_t)(t + 1) * HW);
            float2 c2 = *(const float2*)(bp + (size_t)(t + 2) * HW);
            float2 c3 = *(const float2*)(bp + (size_t)(t + 3) * HW);
            fz0 += focal0(c0.x) + focal0(c1.x) + focal0(c2.x) + focal0(c3.x);
            fz1 += focal0(c0.y) + focal0(c1.y) + focal0(c2.y) + focal0(c3.y);
        }
        s_fzp[q][2*lane] = fz0; s_fzp[q][2*lane+1] = fz1;
    }
    __syncthreads();

    // --- fzs combine ---
    if (tid < 128)
        s_fzs[tid] = s_fzp[0][tid] + s_fzp[1][tid] + s_fzp[2][tid] + s_fzp[3][tid];
    __syncthreads();

    // --- g-phase: wave w handles g = w, w+8, w+16, w+24; 2 pts/lane ---
    float bxa = 0.f, cla = 0.f, dfa = 0.f, np = 0.f;
    unsigned posm = 0;
    int ri = p0 / W;                     // 2 | W -> pair never crosses a row
    float cy  = (float)ri + 0.5f;
    float cx0 = (float)(p0 - ri * W) + 0.5f;

    if (v) {
        int r0 = tile / W, r1 = min(tile + 127, HW - 1) / W;
        float cyLo = (float)r0 + 0.5f, cyHi = (float)r1 + 0.5f;
#pragma unroll
        for (int gi = 0; gi < 4; ++gi) {
            int g = w + 8 * gi;
            float x1 = s_bx[g][0], y1 = s_bx[g][1];
            float x2 = s_bx[g][2], y2 = s_bx[g][3];
            float gx = s_bx[g][4], gy = s_bx[g][5];
            if (anyb) {
                // row-range cull (conservative superset of the exact mask)
                if (!((cyHi > y1) && (y2 > cyLo) &&
                      (cyHi >= gy - RAD) && (cyLo <= gy + RAD))) continue;
            }
#pragma unroll
            for (int j = 0; j < 2; ++j) {
                float cx = cx0 + (float)j;
                float dl = cx - x1, dt = cy - y1, dr = x2 - cx, db = y2 - cy;
                bool mk;
                if (anyb) {
                    mk = (dl > 0.f) && (dt > 0.f) && (dr > 0.f) && (db > 0.f) &&
                         (cx >= gx - RAD) && (cx <= gx + RAD) &&
                         (cy >= gy - RAD) && (cy <= gy + RAD);
                } else {
                    int pt = p0 + j;
                    mk = false;
                    for (int t = 0; t < KTOP; ++t) mk = mk || (s_fb[g][t] == pt);
                }
                if (mk) {
                    posm |= (1u << j);
                    np += 1.f;
                    int ptl = 2 * lane + j, pt = p0 + j;
                    float dv0 = s_dv[0][ptl], dv1 = s_dv[1][ptl];
                    float dv2 = s_dv[2][ptl], dv3 = s_dv[3][ptl];
                    float px1 = cx - dv0, py1 = cy - dv1;
                    float px2 = cx + dv2, py2 = cy + dv3;
                    float pa = (px2 - px1) * (py2 - py1);
                    float ix1 = fmaxf(px1, x1), iy1 = fmaxf(py1, y1);
                    float ix2 = fminf(px2, x2), iy2 = fminf(py2, y2);
                    float iw = fmaxf(ix2 - ix1, 0.f), ih = fmaxf(iy2 - iy1, 0.f);
                    float inter = iw * ih;
                    float ga = (x2 - x1) * (y2 - y1);
                    float iou = inter / (pa + ga - inter + 1e-6f);
                    bxa += 1.f - iou;
                    float ltrb[4] = { dl, dt, dr, db };
#pragma unroll
                    for (int k = 0; k < 4; ++k) {
                        float tt = fminf(fmaxf(ltrb[k], 0.f), 15.9999f);
                        float lf = floorf(tt); int lb = (int)lf;
                        int rb = lb + 1 > REGMAX ? REGMAX : lb + 1;
                        float wl = (float)rb - tt, wr = tt - lf;
                        float lzk = s_lz[k][ptl];
                        float xl = regp[(size_t)(b * 68 + k * BINS + lb) * HW + pt];
                        float xr = regp[(size_t)(b * 68 + k * BINS + rb) * HW + pt];
                        dfa -= (xl - lzk) * wl + (xr - lzk) * wr;
                    }
                    int cc = s_lab[g];
                    float xat = clsp[(size_t)(b * 80 + cc) * HW + pt];
                    cla += s_fzs[ptl] - focal0(xat) + focal_t(xat, iou);
                }
            }
        }
    }
    s_ps[w][lane] = (unsigned char)posm;
    __syncthreads();

    // --- cls_neg: one thread per point ---
    if (tid < 128 && tile + tid < HW) {
        unsigned pg = 0;
#pragma unroll
        for (int wv = 0; wv < 8; ++wv) pg |= s_ps[wv][tid >> 1];
        if (!((pg >> (tid & 1)) & 1u)) cla += s_fzs[tid];
    }

    // --- block reduction: 4 values over 512 threads ---
    float v0 = bxa, v1 = cla, v2 = dfa, v3 = np;
    for (int off = 32; off > 0; off >>= 1) {
        v0 += __shfl_down(v0, off);
        v1 += __shfl_down(v1, off);
        v2 += __shfl_down(v2, off);
        v3 += __shfl_down(v3, off);
    }
    if (lane == 0) { red[w][0] = v0; red[w][1] = v1; red[w][2] = v2; red[w][3] = v3; }
    __syncthreads();
    if (tid == 0) {
        float t0 = 0, t1 = 0, t2 = 0, t3 = 0;
        for (int wv = 0; wv < 8; ++wv) {
            t0 += red[wv][0]; t1 += red[wv][1]; t2 += red[wv][2]; t3 += red[wv][3];
        }
        atomicAdd(&acc[0], t0);
        atomicAdd(&acc[1], t1);
        atomicAdd(&dfln[lvl * NB + b], t2);
        atomicAdd(&npos[lvl * NB + b], t3);
    }

    // --- last block finalizes the output ---
    if (tid == 0) {
        __threadfence();
        s_tick = atomicAdd(cnt, 1);
    }
    __syncthreads();
    if (s_tick == NBLOCKS - 1 && tid < 64) {
        float vs = 0.f;
        if (lane < 48) {
            float n = atomicAdd(&npos[lane], 0.0f);   // coherent read
            float d = atomicAdd(&dfln[lane], 0.0f);
            if (n > 0.f) vs = d / (n * 4.0f);
        }
        for (int off = 32; off > 0; off >>= 1) vs += __shfl_down(vs, off);
        if (lane == 0) {
            float tbv = atomicAdd(&acc[0], 0.0f);
            float tcv = atomicAdd(&acc[1], 0.0f);
            out[0] = 7.5f * tbv + tcv + 1.5f * vs;
            out[1] = tbv; out[2] = tcv; out[3] = vs;
        }
    }
}

extern "C" void kernel_launch(void* const* d_in, const int* in_sizes, int n_in,
                              void* d_out, int out_size, void* d_ws, size_t ws_size,
                              hipStream_t stream) {
    const float* reg0 = (const float*)d_in[0];
    const float* cls0 = (const float*)d_in[1];
    const float* reg1 = (const float*)d_in[2];
    const float* cls1 = (const float*)d_in[3];
    const float* reg2 = (const float*)d_in[4];
    const float* cls2 = (const float*)d_in[5];
    const float* gtb  = (const float*)d_in[6];
    const int*   lab  = (const int*)d_in[7];
    float* out = (float*)d_out;

    char*  ws   = (char*)d_ws;
    float* acc  = (float*)(ws + WS_ACC);
    float* npos = (float*)(ws + WS_NPOS);
    float* dfln = (float*)(ws + WS_DFLN);
    int*   cnt  = (int*)(ws + WS_CNT);

    hipMemsetAsync(d_ws, 0, 612, stream);
    // 128-pt tiles: L0 50, L1 13, L2 4 -> 67 x 16 = 1072 blocks, 512 thr (8 waves)
    k_main_f<<<dim3(67, NB), 512, 0, stream>>>(reg0, cls0, reg1, cls1, reg2, cls2,
                                               gtb, lab,
                                               acc, npos, dfln, cnt, out);
}

// Round 14
// 58.693 us; speedup vs baseline: 1.1134x; 1.1134x over previous
//
#include <hip/hip_runtime.h>
#include <math.h>

#define NCLS 80
#define BINS 17
#define REGMAX 16
#define NG 32
#define NB 16
#define KTOP 10
#define RAD 2.5f

// ---------- workspace layout (bytes) ----------
#define WS_ACC   0
#define WS_NPOS  32
#define WS_DFLN  224
#define WS_CNT   608
#define NBLOCKS  (34 * 16)

// focal_bce with t=0: ce*0.75*p^2   (single exp + single log)
__device__ __forceinline__ float focal0(float x) {
    float e   = __expf(-fabsf(x));
    float inv = 1.0f / (1.0f + e);
    float p   = (x >= 0.0f) ? inv : e * inv;          // sigmoid(x)
    float ce  = fmaxf(x, 0.0f) + __logf(1.0f + e);
    return ce * 0.75f * p * p;
}

__device__ __forceinline__ float focal_t(float x, float t) {
    float e   = __expf(-fabsf(x));
    float inv = 1.0f / (1.0f + e);
    float p   = (x >= 0.0f) ? inv : e * inv;
    float ce  = fmaxf(x, 0.0f) - x * t + __logf(1.0f + e);
    float pt  = p * t + (1.0f - p) * (1.0f - t);
    float at  = 0.25f * t + 0.75f * (1.0f - t);
    float om  = 1.0f - pt;
    return ce * at * om * om;
}

// ---- single fused kernel: 256-pt tiles, 8 waves, float4, FORCED load batch ----
__global__ __launch_bounds__(512, 2) void k_main_f(
    const float* __restrict__ reg0, const float* __restrict__ cls0,
    const float* __restrict__ reg1, const float* __restrict__ cls1,
    const float* __restrict__ reg2, const float* __restrict__ cls2,
    const float* __restrict__ gtb,  const int* __restrict__ lab,
    float* __restrict__ acc, float* __restrict__ npos, float* __restrict__ dfln,
    int* __restrict__ cnt, float* __restrict__ out)
{
    int bx = blockIdx.x;
    int b  = blockIdx.y;
    int lvl, tix, W; const float *regp, *clsp; float inv_s;
    if (bx < 25)      { lvl = 0; tix = bx;      W = 80; regp = reg0; clsp = cls0; inv_s = 0.125f;   }
    else if (bx < 32) { lvl = 1; tix = bx - 25; W = 40; regp = reg1; clsp = cls1; inv_s = 0.0625f;  }
    else              { lvl = 2; tix = bx - 32; W = 20; regp = reg2; clsp = cls2; inv_s = 0.03125f; }
    int HW = W * W;
    int tile = tix * 256;

    int tid  = threadIdx.x;
    int lane = tid & 63;
    int w    = tid >> 6;                 // wave 0..7
    int p0   = tile + 4 * lane;          // this thread's 4 consecutive points
    bool v   = p0 < HW;                  // 4 | HW -> all-or-none per thread
    int pb   = v ? p0 : HW - 4;          // clamped, in-bounds load base

    __shared__ float s_bx[NG][6];        // x1,y1,x2,y2,gcx,gcy (scaled)
    __shared__ int   s_lab[NG];
    __shared__ float s_dv[4][256], s_lz[4][256], s_fzp[4][256], s_fzs[256];
    __shared__ unsigned char s_ps[8][64];
    __shared__ float red[8][4];
    __shared__ int   s_any, s_tick, s_fb[NG][KTOP];

    // --- stage boxes + labels ---
    if (tid == 0) s_any = 0;
    if (tid < NG) {
        int g = tid;
        float4 bb4 = *(const float4*)(gtb + (b * NG + g) * 4);
        float x1 = bb4.x * inv_s, y1 = bb4.y * inv_s;
        float x2 = bb4.z * inv_s, y2 = bb4.w * inv_s;
        s_bx[g][0] = x1; s_bx[g][1] = y1; s_bx[g][2] = x2; s_bx[g][3] = y2;
        s_bx[g][4] = (x1 + x2) * 0.5f; s_bx[g][5] = (y1 + y2) * 0.5f;
        s_lab[g] = lab[b * NG + g];
    }
    __syncthreads();

    // --- any_pos via exact windowed scan (window provably holds all positives) ---
    {
        int g = tid >> 4, wi = tid & 15;         // 16 threads per g
        float x1 = s_bx[g][0], y1 = s_bx[g][1];
        float x2 = s_bx[g][2], y2 = s_bx[g][3];
        float gcx = s_bx[g][4], gcy = s_bx[g][5];
        int jc = (int)floorf(gcx), ic = (int)floorf(gcy);
        bool any = false;
#pragma unroll
        for (int r = 0; r < 6; ++r) {
            int ci = wi + 16 * r;
            if (ci < 81) {
                int j = jc + (ci % 9) - 4, i = ic + (ci / 9) - 4;
                if (j >= 0 && j < W && i >= 0 && i < W) {
                    float cx = (float)j + 0.5f, cy = (float)i + 0.5f;
                    bool m = (cx - x1 > 0.0f) && (cy - y1 > 0.0f) &&
                             (x2 - cx > 0.0f) && (y2 - cy > 0.0f) &&
                             (cx >= gcx - RAD) && (cx <= gcx + RAD) &&
                             (cy >= gcy - RAD) && (cy <= gcy + RAD);
                    any = any || m;
                }
            }
        }
        if (__any(any) && lane == 0) atomicOr(&s_any, 1);
    }
    __syncthreads();
    bool anyb = s_any != 0;

    // --- rare fallback: exact top-10 closest cells per g (block-uniform) ---
    if (!anyb) {
        if (tid < NG) {
            int g = tid;
            float gcx = s_bx[g][4], gcy = s_bx[g][5];
            float bd[KTOP]; int bi[KTOP];
            for (int t = 0; t < KTOP; ++t) { bd[t] = 3.0e38f; bi[t] = 0; }
            for (int p = 0; p < HW; ++p) {
                float cx = (float)(p % W) + 0.5f;
                float cy = (float)(p / W) + 0.5f;
                float dx = cx - gcx, dy = cy - gcy;
                float d = dx * dx + dy * dy;
                if (d < bd[KTOP - 1]) {
                    int t = KTOP - 1;
                    while (t > 0 && d < bd[t - 1]) { bd[t] = bd[t-1]; bi[t] = bi[t-1]; --t; }
                    bd[t] = d; bi[t] = p;
                }
            }
            for (int t = 0; t < KTOP; ++t) s_fb[g][t] = bi[t];
        }
        __syncthreads();
    }

    // --- streaming phase: FORCED-batch float4 loads (17 or 20 in flight/wave) ---
    if (w < 4) {
        // waves 0-3: DFL distribution k = w (17 bins)
        const float* bp = regp + (size_t)(b * 68 + w * BINS) * HW + pb;
        float4 rv[BINS];
#pragma unroll
        for (int t = 0; t < BINS; ++t)
            rv[t] = *(const float4*)(bp + (size_t)t * HW);
        asm volatile("s_waitcnt vmcnt(0)" ::: "memory");   // pins all 17 above
        __builtin_amdgcn_sched_barrier(0);
        float m[4], sm[4], ex[4];
#pragma unroll
        for (int j = 0; j < 4; ++j) { m[j] = -3.0e38f; sm[j] = 0.f; ex[j] = 0.f; }
#pragma unroll
        for (int t = 0; t < BINS; ++t) {
            float xv[4] = { rv[t].x, rv[t].y, rv[t].z, rv[t].w };
#pragma unroll
            for (int j = 0; j < 4; ++j) m[j] = fmaxf(m[j], xv[j]);
        }
#pragma unroll
        for (int t = 0; t < BINS; ++t) {
            float xv[4] = { rv[t].x, rv[t].y, rv[t].z, rv[t].w };
#pragma unroll
            for (int j = 0; j < 4; ++j) {
                float e = __expf(xv[j] - m[j]);
                sm[j] += e; ex[j] += e * (float)t;
            }
        }
        *(float4*)&s_dv[w][4 * lane] =
            make_float4(ex[0] / sm[0], ex[1] / sm[1], ex[2] / sm[2], ex[3] / sm[3]);
        *(float4*)&s_lz[w][4 * lane] =
            make_float4(__logf(sm[0]) + m[0], __logf(sm[1]) + m[1],
                        __logf(sm[2]) + m[2], __logf(sm[3]) + m[3]);
    } else {
        // waves 4-7: 20 focal0 classes each
        int q = w - 4;
        const float* bp = clsp + (size_t)(b * 80 + q * 20) * HW + pb;
        float4 cv[20];
#pragma unroll
        for (int t = 0; t < 20; ++t)
            cv[t] = *(const float4*)(bp + (size_t)t * HW);
        asm volatile("s_waitcnt vmcnt(0)" ::: "memory");   // pins all 20 above
        __builtin_amdgcn_sched_barrier(0);
        float fz[4] = { 0.f, 0.f, 0.f, 0.f };
#pragma unroll
        for (int t = 0; t < 20; ++t) {
            fz[0] += focal0(cv[t].x); fz[1] += focal0(cv[t].y);
            fz[2] += focal0(cv[t].z); fz[3] += focal0(cv[t].w);
        }
        *(float4*)&s_fzp[q][4 * lane] = make_float4(fz[0], fz[1], fz[2], fz[3]);
    }
    __syncthreads();

    // --- fzs combine ---
    if (tid < 256)
        s_fzs[tid] = s_fzp[0][tid] + s_fzp[1][tid] + s_fzp[2][tid] + s_fzp[3][tid];
    __syncthreads();

    // --- g-phase: wave w handles g = w, w+8, w+16, w+24 for its 4 pts/lane ---
    float bxa = 0.f, cla = 0.f, dfa = 0.f, np = 0.f;
    unsigned posm = 0;
    int ri = p0 / W;                     // 4 | W -> group never crosses a row
    float cy  = (float)ri + 0.5f;
    float cxb = (float)(p0 - ri * W) + 0.5f;

    if (v) {
        int r0 = tile / W, r1 = min(tile + 255, HW - 1) / W;
        float cyLo = (float)r0 + 0.5f, cyHi = (float)r1 + 0.5f;
#pragma unroll
        for (int gi = 0; gi < 4; ++gi) {
            int g = w + 8 * gi;          // 8 waves x 4 = all 32 boxes
            float x1 = s_bx[g][0], y1 = s_bx[g][1];
            float x2 = s_bx[g][2], y2 = s_bx[g][3];
            float gx = s_bx[g][4], gy = s_bx[g][5];
            if (anyb) {
                // row-range cull (conservative superset of the exact mask)
                if (!((cyHi > y1) && (y2 > cyLo) &&
                      (cyHi >= gy - RAD) && (cyLo <= gy + RAD))) continue;
            }
#pragma unroll
            for (int j = 0; j < 4; ++j) {
                float cx = cxb + (float)j;
                float dl = cx - x1, dt = cy - y1, dr = x2 - cx, db = y2 - cy;
                bool mk;
                if (anyb) {
                    mk = (dl > 0.f) && (dt > 0.f) && (dr > 0.f) && (db > 0.f) &&
                         (cx >= gx - RAD) && (cx <= gx + RAD) &&
                         (cy >= gy - RAD) && (cy <= gy + RAD);
                } else {
                    int pt = p0 + j;
                    mk = false;
                    for (int t = 0; t < KTOP; ++t) mk = mk || (s_fb[g][t] == pt);
                }
                if (mk) {
                    posm |= (1u << j);
                    np += 1.f;
                    int ptl = 4 * lane + j, pt = p0 + j;
                    float dv0 = s_dv[0][ptl], dv1 = s_dv[1][ptl];
                    float dv2 = s_dv[2][ptl], dv3 = s_dv[3][ptl];
                    float px1 = cx - dv0, py1 = cy - dv1;
                    float px2 = cx + dv2, py2 = cy + dv3;
                    float pa = (px2 - px1) * (py2 - py1);
                    float ix1 = fmaxf(px1, x1), iy1 = fmaxf(py1, y1);
                    float ix2 = fminf(px2, x2), iy2 = fminf(py2, y2);
                    float iw = fmaxf(ix2 - ix1, 0.f), ih = fmaxf(iy2 - iy1, 0.f);
                    float inter = iw * ih;
                    float ga = (x2 - x1) * (y2 - y1);
                    float iou = inter / (pa + ga - inter + 1e-6f);
                    bxa += 1.f - iou;
                    float ltrb[4] = { dl, dt, dr, db };
#pragma unroll
                    for (int k = 0; k < 4; ++k) {
                        float tt = fminf(fmaxf(ltrb[k], 0.f), 15.9999f);
                        float lf = floorf(tt); int lb = (int)lf;
                        int rb = lb + 1 > REGMAX ? REGMAX : lb + 1;
                        float wl = (float)rb - tt, wr = tt - lf;
                        float lzk = s_lz[k][ptl];
                        float xl = regp[(size_t)(b * 68 + k * BINS + lb) * HW + pt];
                        float xr = regp[(size_t)(b * 68 + k * BINS + rb) * HW + pt];
                        dfa -= (xl - lzk) * wl + (xr - lzk) * wr;
                    }
                    int cc = s_lab[g];
                    float xat = clsp[(size_t)(b * 80 + cc) * HW + pt];
                    cla += s_fzs[ptl] - focal0(xat) + focal_t(xat, iou);
                }
            }
        }
    }
    s_ps[w][lane] = (unsigned char)posm;
    __syncthreads();

    // --- cls_neg: one thread per point ---
    if (tid < 256 && tile + tid < HW) {
        unsigned pg = 0;
#pragma unroll
        for (int wv = 0; wv < 8; ++wv) pg |= s_ps[wv][tid >> 2];
        if (!((pg >> (tid & 3)) & 1u)) cla += s_fzs[tid];
    }

    // --- block reduction: 4 values over 512 threads ---
    float v0 = bxa, v1 = cla, v2 = dfa, v3 = np;
    for (int off = 32; off > 0; off >>= 1) {
        v0 += __shfl_down(v0, off);
        v1 += __shfl_down(v1, off);
        v2 += __shfl_down(v2, off);
        v3 += __shfl_down(v3, off);
    }
    if (lane == 0) { red[w][0] = v0; red[w][1] = v1; red[w][2] = v2; red[w][3] = v3; }
    __syncthreads();
    if (tid == 0) {
        float t0 = 0, t1 = 0, t2 = 0, t3 = 0;
        for (int wv = 0; wv < 8; ++wv) {
            t0 += red[wv][0]; t1 += red[wv][1]; t2 += red[wv][2]; t3 += red[wv][3];
        }
        atomicAdd(&acc[0], t0);
        atomicAdd(&acc[1], t1);
        atomicAdd(&dfln[lvl * NB + b], t2);
        atomicAdd(&npos[lvl * NB + b], t3);
    }

    // --- last block finalizes the output ---
    if (tid == 0) {
        __threadfence();
        s_tick = atomicAdd(cnt, 1);
    }
    __syncthreads();
    if (s_tick == NBLOCKS - 1 && tid < 64) {
        float vs = 0.f;
        if (lane < 48) {
            float n = atomicAdd(&npos[lane], 0.0f);   // coherent read
            float d = atomicAdd(&dfln[lane], 0.0f);
            if (n > 0.f) vs = d / (n * 4.0f);
        }
        for (int off = 32; off > 0; off >>= 1) vs += __shfl_down(vs, off);
        if (lane == 0) {
            float tbv = atomicAdd(&acc[0], 0.0f);
            float tcv = atomicAdd(&acc[1], 0.0f);
            out[0] = 7.5f * tbv + tcv + 1.5f * vs;
            out[1] = tbv; out[2] = tcv; out[3] = vs;
        }
    }
}

extern "C" void kernel_launch(void* const* d_in, const int* in_sizes, int n_in,
                              void* d_out, int out_size, void* d_ws, size_t ws_size,
                              hipStream_t stream) {
    const float* reg0 = (const float*)d_in[0];
    const float* cls0 = (const float*)d_in[1];
    const float* reg1 = (const float*)d_in[2];
    const float* cls1 = (const float*)d_in[3];
    const float* reg2 = (const float*)d_in[4];
    const float* cls2 = (const float*)d_in[5];
    const float* gtb  = (const float*)d_in[6];
    const int*   lab  = (const int*)d_in[7];
    float* out = (float*)d_out;

    char*  ws   = (char*)d_ws;
    float* acc  = (float*)(ws + WS_ACC);
    float* npos = (float*)(ws + WS_NPOS);
    float* dfln = (float*)(ws + WS_DFLN);
    int*   cnt  = (int*)(ws + WS_CNT);

    hipMemsetAsync(d_ws, 0, 612, stream);
    // 256-pt tiles: L0 25, L1 7, L2 2 -> 34 x 16 = 544 blocks, 512 thr (8 waves)
    k_main_f<<<dim3(34, NB), 512, 0, stream>>>(reg0, cls0, reg1, cls1, reg2, cls2,
                                               gtb, lab,
                                               acc, npos, dfln, cnt, out);
}